// Round 2
// 283.374 us; speedup vs baseline: 1.0940x; 1.0940x over previous
//
#include <hip/hip_runtime.h>
#include <hip/hip_bf16.h>

#define N_NODES   100000
#define N_EDGES   1000000
#define N_FEAT    136
#define HIDDEN    64
#define N_CLASSES 2
#define NUM_GRAPHS 512

#define NP_PAD    100352          // 98 * 1024
#define SCAN_BLKS 98

#define EPW       128                       // edges per wave (contiguous)
#define NWAVE     7813                      // ceil(1e6 / 128)
#define E_PAD     (NWAVE * EPW)             // 1000064
#define SEG_BLOCKS ((NWAVE + 3) / 4)        // 1954 blocks x 4 waves

#define K1_4 (N_FEAT / 4)              // 34
#define K2_4 (HIDDEN / 4)              // 16

#define K1PAD 160                      // 136 padded to 5*32, row stride (u16)
#define K2PAD 72                       // 64 + 8 pad to break bank alias

#define NB_E  ((N_EDGES + 255) / 256)      // 3907
#define NB_SC ((N_EDGES / 4 + 255) / 256)  // 977

typedef unsigned short ushort_t;
typedef __attribute__((ext_vector_type(8))) short bf16x8;   // MFMA A/B frag
typedef __attribute__((ext_vector_type(4))) float f32x4;    // MFMA C/D frag
typedef __attribute__((ext_vector_type(4))) int i32x4;
typedef __attribute__((ext_vector_type(4))) unsigned short u16x4;

// fp32 -> bf16 (RTNE), bf16 -> fp32
__device__ __forceinline__ ushort_t f2b(float v) {
    unsigned b = __float_as_uint(v);
    return (ushort_t)((b + 0x7FFF + ((b >> 16) & 1)) >> 16);
}
__device__ __forceinline__ float b2f(ushort_t u) {
    return __uint_as_float(((unsigned)u) << 16);
}
__device__ __forceinline__ unsigned pack2(float a, float b) {
    return (unsigned)f2b(a) | ((unsigned)f2b(b) << 16);
}

// ============================ CSR build =====================================
// hist: per-dst degree count; the atomicAdd RETURN is the edge's rank within
// its dst segment -> stored to rank16 so scatter needs no atomics at all.
// gbounds (gstart[g] = lower_bound(batch, g)) fused as the 3 trailing blocks.
__global__ __launch_bounds__(256) void hist_kernel(const int* __restrict__ dst,
                                                   int* __restrict__ cnt,
                                                   ushort_t* __restrict__ rank,
                                                   const int* __restrict__ batch,
                                                   int* __restrict__ gstart) {
    if (blockIdx.x >= NB_E) {
        int g = (blockIdx.x - NB_E) * 256 + threadIdx.x;
        if (g <= NUM_GRAPHS) {
            int lo = 0, hi = N_NODES;
            while (lo < hi) {
                int mid = (lo + hi) >> 1;
                if (batch[mid] < g) lo = mid + 1; else hi = mid;
            }
            gstart[g] = lo;
        }
        return;
    }
    int e = blockIdx.x * 256 + threadIdx.x;
    if (e < N_EDGES) {
        int d = __builtin_nontemporal_load(&dst[e]);
        int r = atomicAdd(&cnt[d], 1);     // rank within segment (max deg << 64K)
        rank[e] = (ushort_t)r;
    }
}

__global__ __launch_bounds__(256) void scan1_kernel(const int* __restrict__ cnt,
                                                    int* __restrict__ row_ptr,
                                                    int* __restrict__ partials) {
    __shared__ int sd[256];
    int b = blockIdx.x, t = threadIdx.x;
    int i0 = b * 1024 + t * 4;
    int c0 = (i0 + 0 < N_NODES) ? cnt[i0 + 0] : 0;
    int c1 = (i0 + 1 < N_NODES) ? cnt[i0 + 1] : 0;
    int c2 = (i0 + 2 < N_NODES) ? cnt[i0 + 2] : 0;
    int c3 = (i0 + 3 < N_NODES) ? cnt[i0 + 3] : 0;
    int tsum = c0 + c1 + c2 + c3;
    sd[t] = tsum;
    __syncthreads();
    for (int off = 1; off < 256; off <<= 1) {
        int v = (t >= off) ? sd[t - off] : 0;
        __syncthreads();
        sd[t] += v;
        __syncthreads();
    }
    int excl = sd[t] - tsum;
    row_ptr[i0 + 0] = excl;
    row_ptr[i0 + 1] = excl + c0;
    row_ptr[i0 + 2] = excl + c0 + c1;
    row_ptr[i0 + 3] = excl + c0 + c1 + c2;
    if (t == 255) partials[b] = sd[255];
}

__global__ __launch_bounds__(128) void scan2_kernel(int* __restrict__ partials) {
    __shared__ int sd[128];
    int t = threadIdx.x;
    int v = (t < SCAN_BLKS) ? partials[t] : 0;
    sd[t] = v;
    __syncthreads();
    for (int off = 1; off < 128; off <<= 1) {
        int u = (t >= off) ? sd[t - off] : 0;
        __syncthreads();
        sd[t] += u;
        __syncthreads();
    }
    partials[t] = sd[t] - v;
}

// scan3: finalize row_ptr, fused dst_sorted expansion, fused dinv, and
// sentinel padding of the edge arrays. (cursor removed — rank-based scatter)
__global__ __launch_bounds__(256) void scan3_kernel(int* __restrict__ row_ptr,
                                                    const int* __restrict__ cnt,
                                                    const int* __restrict__ partials,
                                                    int* __restrict__ dst_sorted,
                                                    int* __restrict__ csr_src,
                                                    float* __restrict__ dinv) {
    int i = blockIdx.x * 256 + threadIdx.x;
    if (i < N_NODES) {
        int v = row_ptr[i] + partials[i >> 10];
        int deg = cnt[i];
        row_ptr[i] = v;
        dinv[i] = rsqrtf((float)(deg + 1));           // +1 self-loop
        for (int j = v; j < v + deg; ++j) dst_sorted[j] = i;
    }
    if (i == N_NODES) {
        row_ptr[N_NODES] = N_EDGES;
        for (int j = N_EDGES; j < E_PAD; ++j) {       // sentinel pad (64 entries)
            dst_sorted[j] = N_NODES;
            csr_src[j] = 0;
        }
    }
}

// atomic-free scatter: pos = row_ptr[d] + rank[e]. One coalesced pass,
// 4 edges/thread; no cursor, no partition passes, no dependent atomic return.
__global__ __launch_bounds__(256) void scatter_kernel(const int* __restrict__ src,
                                                      const int* __restrict__ dst,
                                                      const ushort_t* __restrict__ rank,
                                                      const int* __restrict__ row_ptr,
                                                      int* __restrict__ csr_src) {
    int e0 = (blockIdx.x * 256 + threadIdx.x) * 4;
    if (e0 >= N_EDGES) return;                        // N_EDGES % 4 == 0
    i32x4 s4 = __builtin_nontemporal_load((const i32x4*)&src[e0]);
    i32x4 d4 = __builtin_nontemporal_load((const i32x4*)&dst[e0]);
    u16x4 r4 = *(const u16x4*)&rank[e0];
    int p0 = row_ptr[d4.x] + (int)r4.x;
    int p1 = row_ptr[d4.y] + (int)r4.y;
    int p2 = row_ptr[d4.z] + (int)r4.z;
    int p3 = row_ptr[d4.w] + (int)r4.w;
    csr_src[p0] = s4.x;
    csr_src[p1] = s4.y;
    csr_src[p2] = s4.z;
    csr_src[p3] = s4.w;
}

// ========== MFMA mm1: t' = (x @ W1) * dinv -> bf16  (136 -> 64) =============
// also zero-fills agg (replaces the separate 25.6 MB hipMemsetAsync)
__global__ __launch_bounds__(256) void mm1_kernel(const float* __restrict__ x,
                                                  const float* __restrict__ W1,
                                                  const float* __restrict__ dinv,
                                                  ushort_t* __restrict__ tpb,
                                                  float* __restrict__ agg) {
    __shared__ ushort_t xsb[64 * K1PAD];   // 20480 B, node-major bf16
    __shared__ ushort_t wtb[64 * K1PAD];   // 20480 B, W1 transposed [n][k] bf16
    __shared__ float    dsv[64];
    int t = threadIdx.x;
    int n0 = blockIdx.x * 64;
    {
        // fused agg zero for this block's node range
        for (int i = t; i < 64 * 16; i += 256) {
            int r = i >> 4, c = i & 15;
            int n = n0 + r;
            if (n < N_NODES)
                ((float4*)agg)[n * 16 + c] = make_float4(0.f, 0.f, 0.f, 0.f);
        }
        const float4* x4 = (const float4*)x;
        for (int i = t; i < 64 * K1_4; i += 256) {
            int r = i / K1_4, c = i % K1_4;
            int n = n0 + r; if (n >= N_NODES) n = N_NODES - 1;
            float4 v = x4[(long long)n * K1_4 + c];
            *(uint2*)&xsb[r * K1PAD + 4 * c] =
                make_uint2(pack2(v.x, v.y), pack2(v.z, v.w));
        }
        for (int i = t; i < 64 * 12; i += 256) {
            int r = i / 12, c = i % 12;
            *(unsigned*)&xsb[r * K1PAD + N_FEAT + 2 * c] = 0;
        }
        for (int i = t; i < N_FEAT * HIDDEN; i += 256) {
            int n = i & 63, k = i >> 6;
            wtb[n * K1PAD + k] = f2b(W1[i]);
        }
        for (int i = t; i < 64 * 12; i += 256) {
            int n = i / 12, c = i % 12;
            *(unsigned*)&wtb[n * K1PAD + N_FEAT + 2 * c] = 0;
        }
        if (t < 64) {
            int n = n0 + t; if (n >= N_NODES) n = N_NODES - 1;
            dsv[t] = dinv[n];
        }
    }
    __syncthreads();
    int w = t >> 6, lane = t & 63;
    int quad = lane >> 4, l16 = lane & 15;
    f32x4 acc[4] = {{0,0,0,0},{0,0,0,0},{0,0,0,0},{0,0,0,0}};
#pragma unroll
    for (int kc = 0; kc < K1PAD / 32; ++kc) {
        bf16x8 a = *(const bf16x8*)&xsb[(w * 16 + l16) * K1PAD + kc * 32 + quad * 8];
#pragma unroll
        for (int nt = 0; nt < 4; ++nt) {
            bf16x8 b = *(const bf16x8*)&wtb[(nt * 16 + l16) * K1PAD + kc * 32 + quad * 8];
            acc[nt] = __builtin_amdgcn_mfma_f32_16x16x32_bf16(a, b, acc[nt], 0, 0, 0);
        }
    }
#pragma unroll
    for (int r = 0; r < 4; ++r) {
        int nl = w * 16 + quad * 4 + r;
        int node = n0 + nl;
        if (node < N_NODES) {
            float di = dsv[nl];
#pragma unroll
            for (int nt = 0; nt < 4; ++nt)
                tpb[node * 64 + nt * 16 + l16] = f2b(acc[nt][r] * di);
        }
    }
}

// ========== MFMA mm2 + fused layer-1 epilogue ===============================
__global__ __launch_bounds__(256) void mm2_kernel(float* __restrict__ agg,
                                                  ushort_t* __restrict__ tpb,
                                                  const float* __restrict__ W2,
                                                  const float* __restrict__ dinv,
                                                  const float* __restrict__ bias) {
    __shared__ ushort_t hsb[64 * K2PAD];   // 9216 B
    __shared__ ushort_t wtb[64 * K2PAD];   // 9216 B, W2 transposed [n][k]
    __shared__ float    dsv[64];
    __shared__ float    bsv[64];
    int t = threadIdx.x;
    int n0 = blockIdx.x * 64;
    if (t < 64) {
        int n = n0 + t; if (n >= N_NODES) n = N_NODES - 1;
        dsv[t] = dinv[n];
        bsv[t] = bias[t];
    }
    __syncthreads();
    {
        for (int i = t; i < HIDDEN * HIDDEN; i += 256) {
            int n = i & 63, k = i >> 6;
            wtb[n * K2PAD + k] = f2b(W2[i]);
        }
        for (int i = t; i < 64 * 4; i += 256) {
            int n = i / 4, c = i % 4;
            *(unsigned*)&wtb[n * K2PAD + HIDDEN + 2 * c] = 0;
        }
        // fused epilogue-1: h tile from agg + tpb(self), then zero agg tile
        for (int i = t; i < 64 * 16; i += 256) {
            int r = i >> 4, c = i & 15;            // c = float4 index
            int n_raw = n0 + r;
            int n = (n_raw < N_NODES) ? n_raw : N_NODES - 1;
            float4 va = ((const float4*)agg)[n * 16 + c];
            uint2 ut = *(const uint2*)&tpb[n * 64 + c * 4];
            float di = dsv[r];
            float s0 = b2f((ushort_t)(ut.x & 0xffff));
            float s1 = b2f((ushort_t)(ut.x >> 16));
            float s2 = b2f((ushort_t)(ut.y & 0xffff));
            float s3 = b2f((ushort_t)(ut.y >> 16));
            float h0 = fmaxf(fmaf(va.x + s0, di, bsv[c * 4 + 0]), 0.f);
            float h1 = fmaxf(fmaf(va.y + s1, di, bsv[c * 4 + 1]), 0.f);
            float h2 = fmaxf(fmaf(va.z + s2, di, bsv[c * 4 + 2]), 0.f);
            float h3 = fmaxf(fmaf(va.w + s3, di, bsv[c * 4 + 3]), 0.f);
            *(uint2*)&hsb[r * K2PAD + 4 * c] = make_uint2(pack2(h0, h1), pack2(h2, h3));
            if (n_raw < N_NODES)
                ((float4*)agg)[n * 16 + c] = make_float4(0.f, 0.f, 0.f, 0.f);
        }
        for (int i = t; i < 64 * 4; i += 256) {    // pad [64,72)
            int r = i / 4, c = i % 4;
            *(unsigned*)&hsb[r * K2PAD + HIDDEN + 2 * c] = 0;
        }
    }
    __syncthreads();
    int w = t >> 6, lane = t & 63;
    int quad = lane >> 4, l16 = lane & 15;
    f32x4 acc[4] = {{0,0,0,0},{0,0,0,0},{0,0,0,0},{0,0,0,0}};
#pragma unroll
    for (int kc = 0; kc < 2; ++kc) {
        bf16x8 a = *(const bf16x8*)&hsb[(w * 16 + l16) * K2PAD + kc * 32 + quad * 8];
#pragma unroll
        for (int nt = 0; nt < 4; ++nt) {
            bf16x8 b = *(const bf16x8*)&wtb[(nt * 16 + l16) * K2PAD + kc * 32 + quad * 8];
            acc[nt] = __builtin_amdgcn_mfma_f32_16x16x32_bf16(a, b, acc[nt], 0, 0, 0);
        }
    }
#pragma unroll
    for (int r = 0; r < 4; ++r) {
        int nl = w * 16 + quad * 4 + r;
        int node = n0 + nl;
        if (node < N_NODES) {
            float di = dsv[nl];
#pragma unroll
            for (int nt = 0; nt < 4; ++nt)
                tpb[node * 64 + nt * 16 + l16] = f2b(acc[nt][r] * di);
        }
    }
}

// ======== edge-parallel segmented reduce, contiguous 128-edge waves =========
// dst_sorted sorted => each wave's interior segments are exclusively owned:
// plain 256B stores. Only the first and final flush of a wave use atomicAdd.
__global__ __launch_bounds__(256, 4) void edge_seg_kernel(const int* __restrict__ csr_src,
                                                          const int* __restrict__ dst_sorted,
                                                          const ushort_t* __restrict__ tpb,
                                                          float* __restrict__ agg) {
    int lane = threadIdx.x & 63;
    int wid  = (blockIdx.x * 256 + threadIdx.x) >> 6;
    if (wid >= NWAVE) return;
    int e0 = wid * EPW;

    // 4 coalesced 256B index loads cover the wave's 128 edges
    int sv0 = csr_src[e0 + lane],      sv1 = csr_src[e0 + 64 + lane];
    int dv0 = dst_sorted[e0 + lane],   dv1 = dst_sorted[e0 + 64 + lane];

    float acc = 0.0f;
    int dprev = __builtin_amdgcn_readlane(dv0, 0);
    int nflush = 0;
#pragma unroll
    for (int j = 0; j < 8; ++j) {
        int svj = (j < 4) ? sv0 : sv1;
        int dvj = (j < 4) ? dv0 : dv1;
        int base = (j * 16) & 63;
        int ss[16], dd[16];
#pragma unroll
        for (int k = 0; k < 16; ++k) {
            ss[k] = __builtin_amdgcn_readlane(svj, base + k);
            dd[k] = __builtin_amdgcn_readlane(dvj, base + k);
        }
        float vv[16];
#pragma unroll
        for (int k = 0; k < 16; ++k) vv[k] = b2f(tpb[ss[k] * 64 + lane]);
#pragma unroll
        for (int k = 0; k < 16; ++k) {
            if (dd[k] != dprev) {                 // wave-uniform branch
                if (nflush == 0) atomicAdd(&agg[dprev * 64 + lane], acc);
                else             agg[dprev * 64 + lane] = acc;   // exclusive owner
                ++nflush;
                acc = 0.0f;
                dprev = dd[k];
            }
            acc += vv[k];
        }
    }
    atomicAdd(&agg[dprev * 64 + lane], acc);      // final segment may be shared
}

// ---- layer-2 epilogue + pool + head: one BLOCK per graph, fused out --------
__global__ __launch_bounds__(256) void gpool_kernel(const float* __restrict__ agg,
                                                    const ushort_t* __restrict__ tpb,
                                                    const float* __restrict__ dinv,
                                                    const float* __restrict__ bias,
                                                    const int* __restrict__ gstart,
                                                    const float* __restrict__ Wout,
                                                    const float* __restrict__ bout,
                                                    float* __restrict__ out) {
    __shared__ float red[4][64];
    int lane = threadIdx.x & 63;
    int w = threadIdx.x >> 6;
    int g = blockIdx.x;                      // 512 blocks
    int s = gstart[g], e = gstart[g + 1];
    float b = bias[lane];
    float acc = 0.0f;
    for (int n = s + w; n < e; n += 4) {
        int idx = n * 64 + lane;
        acc += fmaxf(fmaf(agg[idx] + b2f(tpb[idx]), dinv[n], b), 0.0f);
    }
    red[w][lane] = acc;
    __syncthreads();
    if (threadIdx.x < 64) {
        float tot = red[0][lane] + red[1][lane] + red[2][lane] + red[3][lane];
        float p = tot / fmaxf((float)(e - s), 1.0f);      // pooled mean, lane=feature
        float c0 = p * Wout[lane * N_CLASSES + 0];
        float c1 = p * Wout[lane * N_CLASSES + 1];
#pragma unroll
        for (int off = 32; off > 0; off >>= 1) {
            c0 += __shfl_down(c0, off);
            c1 += __shfl_down(c1, off);
        }
        if (lane == 0) {
            out[g * N_CLASSES + 0] = c0 + bout[0];
            out[g * N_CLASSES + 1] = c1 + bout[1];
        }
    }
}

extern "C" void kernel_launch(void* const* d_in, const int* in_sizes, int n_in,
                              void* d_out, int out_size, void* d_ws, size_t ws_size,
                              hipStream_t stream) {
    const float* x     = (const float*)d_in[0];
    const int*   ei    = (const int*)d_in[1];
    const int*   batch = (const int*)d_in[2];
    const float* W1    = (const float*)d_in[3];
    const float* b1    = (const float*)d_in[4];
    const float* W2    = (const float*)d_in[5];
    const float* b2    = (const float*)d_in[6];
    const float* Wout  = (const float*)d_in[7];
    const float* bout  = (const float*)d_in[8];
    float* out = (float*)d_out;

    const int* src = ei;
    const int* dst = ei + N_EDGES;

    // -------- workspace layout (~47 MB) --------
    char* p = (char*)d_ws;
    int*      row_ptr   = (int*)p;      p += (NP_PAD + 256) * sizeof(int);
    int*      cnt       = (int*)p;      p += NP_PAD * sizeof(int);   // histogram
    int*      partials  = (int*)p;      p += 256 * sizeof(int);
    int*      gstart    = (int*)p;      p += (NUM_GRAPHS + 64) * sizeof(int);
    int*      csr_src   = (int*)p;      p += (size_t)E_PAD * sizeof(int);
    int*      dst_sorted= (int*)p;      p += (size_t)E_PAD * sizeof(int);
    float*    dinv      = (float*)p;    p += NP_PAD * sizeof(float);
    ushort_t* tpb       = (ushort_t*)p; p += (size_t)N_NODES * HIDDEN * sizeof(ushort_t);
    float*    agg       = (float*)p;    p += (size_t)(N_NODES + 1) * HIDDEN * sizeof(float);
    // rank16 (2 MB) is live only hist->scatter; agg is live only mm1 onward:
    // alias it onto agg to avoid growing the workspace.
    ushort_t* rank16    = (ushort_t*)agg;

    const int NB_MM = (N_NODES + 63) / 64;    // 1563 (last block guarded)

    // -------- CSR build (rank-based, atomic-free scatter) + graph bounds ----
    hipMemsetAsync(cnt, 0, NP_PAD * sizeof(int), stream);
    hist_kernel<<<NB_E + 3, 256, 0, stream>>>(dst, cnt, rank16, batch, gstart);
    scan1_kernel<<<SCAN_BLKS, 256, 0, stream>>>(cnt, row_ptr, partials);
    scan2_kernel<<<1, 128, 0, stream>>>(partials);
    scan3_kernel<<<NP_PAD / 256 + 1, 256, 0, stream>>>(row_ptr, cnt, partials,
                                                       dst_sorted, csr_src, dinv);
    scatter_kernel<<<NB_SC, 256, 0, stream>>>(src, dst, rank16, row_ptr, csr_src);

    // -------- layer 1 (mm1 also zero-fills agg, replacing memset) --------
    mm1_kernel<<<NB_MM, 256, 0, stream>>>(x, W1, dinv, tpb, agg);
    edge_seg_kernel<<<SEG_BLOCKS, 256, 0, stream>>>(csr_src, dst_sorted, tpb, agg);

    // -------- layer 2: mm2 fuses epilogue-1 (b1) + agg re-zero --------
    mm2_kernel<<<NB_MM, 256, 0, stream>>>(agg, tpb, W2, dinv, b1);
    edge_seg_kernel<<<SEG_BLOCKS, 256, 0, stream>>>(csr_src, dst_sorted, tpb, agg);

    // -------- pool + head fused --------
    gpool_kernel<<<NUM_GRAPHS, 256, 0, stream>>>(agg, tpb, dinv, b2, gstart,
                                                 Wout, bout, out);
}

// Round 3
// 264.009 us; speedup vs baseline: 1.1743x; 1.0733x over previous
//
#include <hip/hip_runtime.h>
#include <hip/hip_bf16.h>

#define N_NODES   100000
#define N_EDGES   1000000
#define N_FEAT    136
#define HIDDEN    64
#define N_CLASSES 2
#define NUM_GRAPHS 512

#define NP_PAD    100352          // 98 * 1024
#define SCAN_BLKS 98

#define EPW       128                       // edges per wave (contiguous)
#define NWAVE     7813                      // ceil(1e6 / 128)
#define E_PAD     (NWAVE * EPW)             // 1000064
#define SEG_BLOCKS ((NWAVE + 3) / 4)        // 1954 blocks x 4 waves

#define K1_4 (N_FEAT / 4)              // 34
#define K2_4 (HIDDEN / 4)              // 16

#define K1PAD 160                      // 136 padded to 5*32, row stride (u16)
#define K2PAD 72                       // 64 + 8 pad to break bank alias

#define NB_E    ((N_EDGES + 255) / 256)      // 3907
#define NB_SC   ((N_EDGES / 4 + 255) / 256)  // 977
#define NB_HIST (NB_E + 3)                   // hist blocks + 3 gbounds blocks = 3910
#define NB_MM   ((N_NODES + 63) / 64)        // 1563
// striped fusion: per 7 blocks, 2 are mm1-role, 5 are hist-role.
// grid 5474 covers mb 0..1562 and hb 0..3909 exactly (1 idle slot).
#define FUSED_GRID 5474

typedef unsigned short ushort_t;
typedef __attribute__((ext_vector_type(8))) short bf16x8;   // MFMA A/B frag
typedef __attribute__((ext_vector_type(4))) float f32x4;    // MFMA C/D frag
typedef __attribute__((ext_vector_type(4))) int i32x4;
typedef __attribute__((ext_vector_type(4))) unsigned short u16x4;

// fp32 -> bf16 (RTNE), bf16 -> fp32
__device__ __forceinline__ ushort_t f2b(float v) {
    unsigned b = __float_as_uint(v);
    return (ushort_t)((b + 0x7FFF + ((b >> 16) & 1)) >> 16);
}
__device__ __forceinline__ float b2f(ushort_t u) {
    return __uint_as_float(((unsigned)u) << 16);
}
__device__ __forceinline__ unsigned pack2(float a, float b) {
    return (unsigned)f2b(a) | ((unsigned)f2b(b) << 16);
}

// ============ fused: hist (atomic-bound) ∥ mm1 (MFMA-bound) ∥ gbounds =======
// hist: per-dst degree count; the atomicAdd RETURN is the edge's rank within
// its dst segment (rank-based atomic-free scatter downstream).
// mm1: tpb = bf16(x @ W1) UNSCALED (dinv de-folded -> no CSR dependency).
// Striped block roles so every CU co-hosts atomic-issuing waves and MFMA
// waves: hist saturates the device atomic unit, mm1 rides the idle pipes.
__global__ __launch_bounds__(256) void fused_hist_mm1_kernel(
        const int* __restrict__ dst, int* __restrict__ cnt,
        ushort_t* __restrict__ rank,
        const int* __restrict__ batch, int* __restrict__ gstart,
        const float* __restrict__ x, const float* __restrict__ W1,
        ushort_t* __restrict__ tpb) {
    __shared__ ushort_t xsb[64 * K1PAD];   // 20480 B, node-major bf16
    __shared__ ushort_t wtb[64 * K1PAD];   // 20480 B, W1 transposed [n][k] bf16
    int t = threadIdx.x;
    int gq = blockIdx.x / 7, gr = blockIdx.x % 7;

    if (gr >= 2) {                          // ---- hist / gbounds role ----
        int hb = gq * 5 + (gr - 2);
        if (hb >= NB_HIST) return;
        if (hb >= NB_E) {                   // gbounds: lower_bound(batch, g)
            int g = (hb - NB_E) * 256 + t;
            if (g <= NUM_GRAPHS) {
                int lo = 0, hi = N_NODES;
                while (lo < hi) {
                    int mid = (lo + hi) >> 1;
                    if (batch[mid] < g) lo = mid + 1; else hi = mid;
                }
                gstart[g] = lo;
            }
            return;
        }
        int e = hb * 256 + t;
        if (e < N_EDGES) {
            int d = __builtin_nontemporal_load(&dst[e]);
            int r = atomicAdd(&cnt[d], 1);  // rank within segment (deg << 64K)
            __builtin_nontemporal_store((ushort_t)r, &rank[e]);
        }
        return;
    }

    // ---- mm1 role ----
    int mb = gq * 2 + gr;
    if (mb >= NB_MM) return;
    int n0 = mb * 64;
    {
        const float4* x4 = (const float4*)x;
        for (int i = t; i < 64 * K1_4; i += 256) {
            int r = i / K1_4, c = i % K1_4;
            int n = n0 + r; if (n >= N_NODES) n = N_NODES - 1;
            float4 v = x4[(long long)n * K1_4 + c];
            *(uint2*)&xsb[r * K1PAD + 4 * c] =
                make_uint2(pack2(v.x, v.y), pack2(v.z, v.w));
        }
        for (int i = t; i < 64 * 12; i += 256) {
            int r = i / 12, c = i % 12;
            *(unsigned*)&xsb[r * K1PAD + N_FEAT + 2 * c] = 0;
        }
        for (int i = t; i < N_FEAT * HIDDEN; i += 256) {
            int n = i & 63, k = i >> 6;
            wtb[n * K1PAD + k] = f2b(W1[i]);
        }
        for (int i = t; i < 64 * 12; i += 256) {
            int n = i / 12, c = i % 12;
            *(unsigned*)&wtb[n * K1PAD + N_FEAT + 2 * c] = 0;
        }
    }
    __syncthreads();
    int w = t >> 6, lane = t & 63;
    int quad = lane >> 4, l16 = lane & 15;
    f32x4 acc[4] = {{0,0,0,0},{0,0,0,0},{0,0,0,0},{0,0,0,0}};
#pragma unroll
    for (int kc = 0; kc < K1PAD / 32; ++kc) {
        bf16x8 a = *(const bf16x8*)&xsb[(w * 16 + l16) * K1PAD + kc * 32 + quad * 8];
#pragma unroll
        for (int nt = 0; nt < 4; ++nt) {
            bf16x8 b = *(const bf16x8*)&wtb[(nt * 16 + l16) * K1PAD + kc * 32 + quad * 8];
            acc[nt] = __builtin_amdgcn_mfma_f32_16x16x32_bf16(a, b, acc[nt], 0, 0, 0);
        }
    }
#pragma unroll
    for (int r = 0; r < 4; ++r) {
        int nl = w * 16 + quad * 4 + r;
        int node = n0 + nl;
        if (node < N_NODES) {
#pragma unroll
            for (int nt = 0; nt < 4; ++nt)
                tpb[node * 64 + nt * 16 + l16] = f2b(acc[nt][r]);   // unscaled
        }
    }
}

__global__ __launch_bounds__(256) void scan1_kernel(const int* __restrict__ cnt,
                                                    int* __restrict__ row_ptr,
                                                    int* __restrict__ partials) {
    __shared__ int sd[256];
    int b = blockIdx.x, t = threadIdx.x;
    int i0 = b * 1024 + t * 4;
    int c0 = (i0 + 0 < N_NODES) ? cnt[i0 + 0] : 0;
    int c1 = (i0 + 1 < N_NODES) ? cnt[i0 + 1] : 0;
    int c2 = (i0 + 2 < N_NODES) ? cnt[i0 + 2] : 0;
    int c3 = (i0 + 3 < N_NODES) ? cnt[i0 + 3] : 0;
    int tsum = c0 + c1 + c2 + c3;
    sd[t] = tsum;
    __syncthreads();
    for (int off = 1; off < 256; off <<= 1) {
        int v = (t >= off) ? sd[t - off] : 0;
        __syncthreads();
        sd[t] += v;
        __syncthreads();
    }
    int excl = sd[t] - tsum;
    row_ptr[i0 + 0] = excl;
    row_ptr[i0 + 1] = excl + c0;
    row_ptr[i0 + 2] = excl + c0 + c1;
    row_ptr[i0 + 3] = excl + c0 + c1 + c2;
    if (t == 255) partials[b] = sd[255];
}

__global__ __launch_bounds__(128) void scan2_kernel(int* __restrict__ partials) {
    __shared__ int sd[128];
    int t = threadIdx.x;
    int v = (t < SCAN_BLKS) ? partials[t] : 0;
    sd[t] = v;
    __syncthreads();
    for (int off = 1; off < 128; off <<= 1) {
        int u = (t >= off) ? sd[t - off] : 0;
        __syncthreads();
        sd[t] += u;
        __syncthreads();
    }
    partials[t] = sd[t] - v;
}

// scan3: finalize row_ptr, fused dst_sorted expansion, fused dinv, and
// sentinel padding of the edge arrays.
__global__ __launch_bounds__(256) void scan3_kernel(int* __restrict__ row_ptr,
                                                    const int* __restrict__ cnt,
                                                    const int* __restrict__ partials,
                                                    int* __restrict__ dst_sorted,
                                                    int* __restrict__ csr_src,
                                                    float* __restrict__ dinv) {
    int i = blockIdx.x * 256 + threadIdx.x;
    if (i < N_NODES) {
        int v = row_ptr[i] + partials[i >> 10];
        int deg = cnt[i];
        row_ptr[i] = v;
        dinv[i] = rsqrtf((float)(deg + 1));           // +1 self-loop
        for (int j = v; j < v + deg; ++j) dst_sorted[j] = i;
    }
    if (i == N_NODES) {
        row_ptr[N_NODES] = N_EDGES;
        for (int j = N_EDGES; j < E_PAD; ++j) {       // sentinel pad (64 entries)
            dst_sorted[j] = N_NODES;
            csr_src[j] = 0;
        }
    }
}

// atomic-free scatter: pos = row_ptr[d] + rank[e]. One coalesced pass,
// 4 edges/thread; no cursor, no partition passes, no dependent atomic return.
__global__ __launch_bounds__(256) void scatter_kernel(const int* __restrict__ src,
                                                      const int* __restrict__ dst,
                                                      const ushort_t* __restrict__ rank,
                                                      const int* __restrict__ row_ptr,
                                                      int* __restrict__ csr_src) {
    int e0 = (blockIdx.x * 256 + threadIdx.x) * 4;
    if (e0 >= N_EDGES) return;                        // N_EDGES % 4 == 0
    i32x4 s4 = __builtin_nontemporal_load((const i32x4*)&src[e0]);
    i32x4 d4 = __builtin_nontemporal_load((const i32x4*)&dst[e0]);
    u16x4 r4 = *(const u16x4*)&rank[e0];
    int p0 = row_ptr[d4.x] + (int)r4.x;
    int p1 = row_ptr[d4.y] + (int)r4.y;
    int p2 = row_ptr[d4.z] + (int)r4.z;
    int p3 = row_ptr[d4.w] + (int)r4.w;
    csr_src[p0] = s4.x;
    csr_src[p1] = s4.y;
    csr_src[p2] = s4.z;
    csr_src[p3] = s4.w;
}

// ========== MFMA mm2 + fused layer-1 epilogue ===============================
// layer-1 tpb is UNSCALED now: self-term needs an extra *di.
__global__ __launch_bounds__(256) void mm2_kernel(float* __restrict__ agg,
                                                  ushort_t* __restrict__ tpb,
                                                  const float* __restrict__ W2,
                                                  const float* __restrict__ dinv,
                                                  const float* __restrict__ bias) {
    __shared__ ushort_t hsb[64 * K2PAD];   // 9216 B
    __shared__ ushort_t wtb[64 * K2PAD];   // 9216 B, W2 transposed [n][k]
    __shared__ float    dsv[64];
    __shared__ float    bsv[64];
    int t = threadIdx.x;
    int n0 = blockIdx.x * 64;
    if (t < 64) {
        int n = n0 + t; if (n >= N_NODES) n = N_NODES - 1;
        dsv[t] = dinv[n];
        bsv[t] = bias[t];
    }
    __syncthreads();
    {
        for (int i = t; i < HIDDEN * HIDDEN; i += 256) {
            int n = i & 63, k = i >> 6;
            wtb[n * K2PAD + k] = f2b(W2[i]);
        }
        for (int i = t; i < 64 * 4; i += 256) {
            int n = i / 4, c = i % 4;
            *(unsigned*)&wtb[n * K2PAD + HIDDEN + 2 * c] = 0;
        }
        // fused epilogue-1: h tile from agg + tpb(self)*di, then zero agg tile
        for (int i = t; i < 64 * 16; i += 256) {
            int r = i >> 4, c = i & 15;            // c = float4 index
            int n_raw = n0 + r;
            int n = (n_raw < N_NODES) ? n_raw : N_NODES - 1;
            float4 va = ((const float4*)agg)[n * 16 + c];
            uint2 ut = *(const uint2*)&tpb[n * 64 + c * 4];
            float di = dsv[r];
            float s0 = b2f((ushort_t)(ut.x & 0xffff)) * di;
            float s1 = b2f((ushort_t)(ut.x >> 16)) * di;
            float s2 = b2f((ushort_t)(ut.y & 0xffff)) * di;
            float s3 = b2f((ushort_t)(ut.y >> 16)) * di;
            float h0 = fmaxf(fmaf(va.x + s0, di, bsv[c * 4 + 0]), 0.f);
            float h1 = fmaxf(fmaf(va.y + s1, di, bsv[c * 4 + 1]), 0.f);
            float h2 = fmaxf(fmaf(va.z + s2, di, bsv[c * 4 + 2]), 0.f);
            float h3 = fmaxf(fmaf(va.w + s3, di, bsv[c * 4 + 3]), 0.f);
            *(uint2*)&hsb[r * K2PAD + 4 * c] = make_uint2(pack2(h0, h1), pack2(h2, h3));
            if (n_raw < N_NODES)
                ((float4*)agg)[n * 16 + c] = make_float4(0.f, 0.f, 0.f, 0.f);
        }
        for (int i = t; i < 64 * 4; i += 256) {    // pad [64,72)
            int r = i / 4, c = i % 4;
            *(unsigned*)&hsb[r * K2PAD + HIDDEN + 2 * c] = 0;
        }
    }
    __syncthreads();
    int w = t >> 6, lane = t & 63;
    int quad = lane >> 4, l16 = lane & 15;
    f32x4 acc[4] = {{0,0,0,0},{0,0,0,0},{0,0,0,0},{0,0,0,0}};
#pragma unroll
    for (int kc = 0; kc < 2; ++kc) {
        bf16x8 a = *(const bf16x8*)&hsb[(w * 16 + l16) * K2PAD + kc * 32 + quad * 8];
#pragma unroll
        for (int nt = 0; nt < 4; ++nt) {
            bf16x8 b = *(const bf16x8*)&wtb[(nt * 16 + l16) * K2PAD + kc * 32 + quad * 8];
            acc[nt] = __builtin_amdgcn_mfma_f32_16x16x32_bf16(a, b, acc[nt], 0, 0, 0);
        }
    }
#pragma unroll
    for (int r = 0; r < 4; ++r) {
        int nl = w * 16 + quad * 4 + r;
        int node = n0 + nl;
        if (node < N_NODES) {
            float di = dsv[nl];
#pragma unroll
            for (int nt = 0; nt < 4; ++nt)
                tpb[node * 64 + nt * 16 + l16] = f2b(acc[nt][r] * di);  // scaled
        }
    }
}

// ======== edge-parallel segmented reduce, contiguous 128-edge waves =========
// SCALE_SRC: layer-1 applies dinv[src] per edge (tpb unscaled); layer-2 tpb
// already carries dinv -> no scale.
template<bool SCALE_SRC>
__global__ __launch_bounds__(256, 4) void edge_seg_kernel(const int* __restrict__ csr_src,
                                                          const int* __restrict__ dst_sorted,
                                                          const ushort_t* __restrict__ tpb,
                                                          const float* __restrict__ dinv,
                                                          float* __restrict__ agg) {
    int lane = threadIdx.x & 63;
    int wid  = (blockIdx.x * 256 + threadIdx.x) >> 6;
    if (wid >= NWAVE) return;
    int e0 = wid * EPW;

    // 4 coalesced 256B index loads cover the wave's 128 edges
    int sv0 = csr_src[e0 + lane],      sv1 = csr_src[e0 + 64 + lane];
    int dv0 = dst_sorted[e0 + lane],   dv1 = dst_sorted[e0 + 64 + lane];

    float acc = 0.0f;
    int dprev = __builtin_amdgcn_readlane(dv0, 0);
    int nflush = 0;
#pragma unroll
    for (int j = 0; j < 8; ++j) {
        int svj = (j < 4) ? sv0 : sv1;
        int dvj = (j < 4) ? dv0 : dv1;
        int base = (j * 16) & 63;
        int ss[16], dd[16];
#pragma unroll
        for (int k = 0; k < 16; ++k) {
            ss[k] = __builtin_amdgcn_readlane(svj, base + k);
            dd[k] = __builtin_amdgcn_readlane(dvj, base + k);
        }
        float vv[16];
#pragma unroll
        for (int k = 0; k < 16; ++k) {
            float v = b2f(tpb[ss[k] * 64 + lane]);
            if (SCALE_SRC) v *= dinv[ss[k]];      // wave-uniform broadcast load
            vv[k] = v;
        }
#pragma unroll
        for (int k = 0; k < 16; ++k) {
            if (dd[k] != dprev) {                 // wave-uniform branch
                if (nflush == 0) atomicAdd(&agg[dprev * 64 + lane], acc);
                else             agg[dprev * 64 + lane] = acc;   // exclusive owner
                ++nflush;
                acc = 0.0f;
                dprev = dd[k];
            }
            acc += vv[k];
        }
    }
    atomicAdd(&agg[dprev * 64 + lane], acc);      // final segment may be shared
}

// ---- layer-2 epilogue + pool + head: one BLOCK per graph, fused out --------
__global__ __launch_bounds__(256) void gpool_kernel(const float* __restrict__ agg,
                                                    const ushort_t* __restrict__ tpb,
                                                    const float* __restrict__ dinv,
                                                    const float* __restrict__ bias,
                                                    const int* __restrict__ gstart,
                                                    const float* __restrict__ Wout,
                                                    const float* __restrict__ bout,
                                                    float* __restrict__ out) {
    __shared__ float red[4][64];
    int lane = threadIdx.x & 63;
    int w = threadIdx.x >> 6;
    int g = blockIdx.x;                      // 512 blocks
    int s = gstart[g], e = gstart[g + 1];
    float b = bias[lane];
    float acc = 0.0f;
    for (int n = s + w; n < e; n += 4) {
        int idx = n * 64 + lane;
        acc += fmaxf(fmaf(agg[idx] + b2f(tpb[idx]), dinv[n], b), 0.0f);
    }
    red[w][lane] = acc;
    __syncthreads();
    if (threadIdx.x < 64) {
        float tot = red[0][lane] + red[1][lane] + red[2][lane] + red[3][lane];
        float p = tot / fmaxf((float)(e - s), 1.0f);      // pooled mean, lane=feature
        float c0 = p * Wout[lane * N_CLASSES + 0];
        float c1 = p * Wout[lane * N_CLASSES + 1];
#pragma unroll
        for (int off = 32; off > 0; off >>= 1) {
            c0 += __shfl_down(c0, off);
            c1 += __shfl_down(c1, off);
        }
        if (lane == 0) {
            out[g * N_CLASSES + 0] = c0 + bout[0];
            out[g * N_CLASSES + 1] = c1 + bout[1];
        }
    }
}

extern "C" void kernel_launch(void* const* d_in, const int* in_sizes, int n_in,
                              void* d_out, int out_size, void* d_ws, size_t ws_size,
                              hipStream_t stream) {
    const float* x     = (const float*)d_in[0];
    const int*   ei    = (const int*)d_in[1];
    const int*   batch = (const int*)d_in[2];
    const float* W1    = (const float*)d_in[3];
    const float* b1    = (const float*)d_in[4];
    const float* W2    = (const float*)d_in[5];
    const float* b2    = (const float*)d_in[6];
    const float* Wout  = (const float*)d_in[7];
    const float* bout  = (const float*)d_in[8];
    float* out = (float*)d_out;

    const int* src = ei;
    const int* dst = ei + N_EDGES;

    // -------- workspace layout (~47 MB) --------
    char* p = (char*)d_ws;
    int*      row_ptr   = (int*)p;      p += (NP_PAD + 256) * sizeof(int);
    int*      cnt       = (int*)p;      p += NP_PAD * sizeof(int);   // histogram
    int*      partials  = (int*)p;      p += 256 * sizeof(int);
    int*      gstart    = (int*)p;      p += (NUM_GRAPHS + 64) * sizeof(int);
    int*      csr_src   = (int*)p;      p += (size_t)E_PAD * sizeof(int);
    int*      dst_sorted= (int*)p;      p += (size_t)E_PAD * sizeof(int);
    float*    dinv      = (float*)p;    p += NP_PAD * sizeof(float);
    ushort_t* tpb       = (ushort_t*)p; p += (size_t)N_NODES * HIDDEN * sizeof(ushort_t);
    float*    agg       = (float*)p;    p += (size_t)(N_NODES + 1) * HIDDEN * sizeof(float);
    // rank16 (2 MB) is live only hist->scatter; agg is first written by the
    // post-scatter memset: alias rank16 onto agg (mm1 no longer touches agg).
    ushort_t* rank16    = (ushort_t*)agg;

    // -------- fused: CSR hist ∥ mm1 ∥ graph bounds --------
    hipMemsetAsync(cnt, 0, NP_PAD * sizeof(int), stream);
    fused_hist_mm1_kernel<<<FUSED_GRID, 256, 0, stream>>>(dst, cnt, rank16,
                                                          batch, gstart,
                                                          x, W1, tpb);
    scan1_kernel<<<SCAN_BLKS, 256, 0, stream>>>(cnt, row_ptr, partials);
    scan2_kernel<<<1, 128, 0, stream>>>(partials);
    scan3_kernel<<<NP_PAD / 256 + 1, 256, 0, stream>>>(row_ptr, cnt, partials,
                                                       dst_sorted, csr_src, dinv);
    scatter_kernel<<<NB_SC, 256, 0, stream>>>(src, dst, rank16, row_ptr, csr_src);

    // agg first use is AFTER scatter consumed rank16 (aliased)
    hipMemsetAsync(agg, 0, (size_t)(N_NODES + 1) * HIDDEN * sizeof(float), stream);

    // -------- layer 1 (dinv[src] applied per-edge) --------
    edge_seg_kernel<true><<<SEG_BLOCKS, 256, 0, stream>>>(csr_src, dst_sorted,
                                                          tpb, dinv, agg);

    // -------- layer 2: mm2 fuses epilogue-1 (b1) + agg re-zero --------
    mm2_kernel<<<NB_MM, 256, 0, stream>>>(agg, tpb, W2, dinv, b1);
    edge_seg_kernel<false><<<SEG_BLOCKS, 256, 0, stream>>>(csr_src, dst_sorted,
                                                           tpb, dinv, agg);

    // -------- pool + head fused --------
    gpool_kernel<<<NUM_GRAPHS, 256, 0, stream>>>(agg, tpb, dinv, b2, gstart,
                                                 Wout, bout, out);
}